// Round 6
// baseline (179.009 us; speedup 1.0000x reference)
//
#include <hip/hip_runtime.h>
#include <hip/hip_fp16.h>

#define OUT_UNITS 128
#define RPB 64                 // rows per block (grid 256 = 1 block/CU)
#define NTHREADS 1024          // 16 waves
#define NW 16
#define SROWS 64               // w-rows per sweep stage
#define SBYTES (SROWS * OUT_UNITS * 2)   // 16 KB fp16
#define NSTAGES 128            // 8192 / 64
#define RING 6                 // LDS ring slots (96 KB)
#define NKEY (NSTAGES * NW)    // 2048 buckets: (stage, wave)
#define CV_CAP 4608            // block nnz: mean 4096, sigma 64 -> +8 sigma

#define GLOBAL_AS __attribute__((address_space(1)))
#define LDS_AS    __attribute__((address_space(3)))

// ---------------- Kernel 0: fused prep (round-0 proven) ---------------------
__global__ void prep(const float4* __restrict__ w4, uint2* __restrict__ wh, int n4,
                     const int* __restrict__ rows, int* __restrict__ row_start,
                     int nnz, int n_rows) {
    int i = blockIdx.x * blockDim.x + threadIdx.x;
    if (i < n4) {
        float4 f = w4[i];
        __half2 h01 = __floats2half2_rn(f.x, f.y);
        __half2 h23 = __floats2half2_rn(f.z, f.w);
        wh[i] = make_uint2(*(unsigned*)&h01, *(unsigned*)&h23);
    }
    if (i < nnz) {
        int cur = rows[i];
        if (i == 0) {
            for (int r = 0; r <= cur; ++r) row_start[r] = 0;
        } else {
            int prev = rows[i - 1];
            for (int r = prev + 1; r <= cur; ++r) row_start[r] = i;
        }
        if (i == nnz - 1) {
            for (int r = cur + 1; r <= n_rows; ++r) row_start[r] = nnz;
        }
    }
}

// ---------------- Kernel 1: counted-vmcnt table-sweep SpMM ------------------
// Round-5 lesson: __syncthreads() per stage = s_waitcnt vmcnt(0) before
// s_barrier -> drained the global_load_lds ring every stage; each stage paid
// full L2 latency serially (2400 cyc/stage vs 600 modeled). Round 6 applies
// the T3/T4 counted-vmcnt pattern: raw s_barrier (no drain), loads stay in
// flight across barriers. Schedule per group g (2 stages): issue {2g+4,2g+5};
// consume {2g,2g+1} with NO wait (their loads landed before the PREVIOUS
// barrier: each wave ran vmcnt(2) at end of group g-1, landing {2g,2g+1} and
// leaving {2g+2,2g+3} in flight; the barrier publishes cross-wave); then
// vmcnt(2); barrier. Ring-6 slot reuse distance = 3 groups > barrier skew.
// Consume rebalance: buckets per (stage, wave) (lambda=2), wave-uniform
// scalar loop (no exec divergence); all 4 quarters broadcast-read the same
// 256B w-slice, FMA predicated on entry.quarter == quarter. 4-wide entry
// blocks pipeline the dependent cv->w LDS reads.
__global__ __launch_bounds__(NTHREADS, 4)
void spmm_sweep3(const float* __restrict__ vals,
                 const __half* __restrict__ wh,
                 const int* __restrict__ cols,
                 const int* __restrict__ row_start,
                 float* __restrict__ out) {
    __shared__ __align__(16) char wbuf[RING][SBYTES];  // 96 KB
    __shared__ int2     cv[CV_CAP];                    // 36 KB {quarter<<6|cl, v}
    __shared__ unsigned lptr[NKEY + 1];                // 8 KB bucket starts
    __shared__ unsigned lcur[NKEY];                    // 8 KB scatter cursors
    __shared__ unsigned wtot[NW], woff[NW];

    const int tid     = threadIdx.x;
    const int wave    = __builtin_amdgcn_readfirstlane(tid >> 6);
    const int lane    = tid & 63;
    const int quarter = lane >> 4;
    const int sub     = lane & 15;
    const int loff    = sub << 4;
    const int r0      = blockIdx.x * RPB;

    // ---- sort phase: counting-sort nnz by (stage, owning wave) ----
    for (int k = tid; k < NKEY; k += NTHREADS) lptr[k] = 0;
    __syncthreads();

    int rs[5];
#pragma unroll
    for (int j = 0; j <= 4; ++j) rs[j] = row_start[r0 + wave * 4 + j];
    const int g0 = row_start[r0];

#pragma unroll
    for (int j = 0; j < 4; ++j)
        for (int i = rs[j] + lane; i < rs[j + 1]; i += 64)
            atomicAdd(&lptr[((unsigned)cols[i] >> 6) * NW + wave], 1u);
    __syncthreads();

    // exclusive prefix over 2048 buckets (2 per thread)
    const int kb = wave * 128 + lane * 2;
    unsigned h0 = lptr[kb], h1 = lptr[kb + 1];
    unsigned lsum = h0 + h1, sc = lsum;
#pragma unroll
    for (int d = 1; d < 64; d <<= 1) {
        unsigned u = __shfl_up(sc, d);
        if (lane >= d) sc += u;
    }
    if (lane == 63) wtot[wave] = sc;
    const unsigned lex = sc - lsum;
    __syncthreads();
    if (wave == 0 && lane < NW) {
        unsigned t = wtot[lane], s2 = t;
#pragma unroll
        for (int d = 1; d < NW; d <<= 1) {
            unsigned u = __shfl_up(s2, d);
            if (lane >= d) s2 += u;
        }
        woff[lane] = s2 - t;
    }
    __syncthreads();
    unsigned base = woff[wave] + lex;
    lptr[kb] = base;          lcur[kb] = base;
    lptr[kb + 1] = base + h0; lcur[kb + 1] = base + h0;
    if (tid == 0) lptr[NKEY] = (unsigned)(row_start[r0 + RPB] - g0);
    __syncthreads();

#pragma unroll
    for (int j = 0; j < 4; ++j)
        for (int i = rs[j] + lane; i < rs[j + 1]; i += 64) {
            int c = cols[i];
            float v = vals[i];
            unsigned pos = atomicAdd(&lcur[((unsigned)c >> 6) * NW + wave], 1u);
            cv[pos] = make_int2((j << 6) | (c & 63), __float_as_int(v));
        }
    __syncthreads();   // full drain: vmcnt clean before stream discipline

    // ---- sweep phase ----
    const char* __restrict__ whb = (const char*)wh;
    float4 accA = make_float4(0.f, 0.f, 0.f, 0.f);
    float4 accB = make_float4(0.f, 0.f, 0.f, 0.f);

#define ISSUE(t)                                                               \
    {                                                                          \
        const char* src_ = whb + (size_t)(t) * SBYTES + (wave << 10) + (lane << 4); \
        char* dst_ = &wbuf[(t) % RING][wave << 10];                            \
        __builtin_amdgcn_global_load_lds((const GLOBAL_AS void*)src_,          \
                                         (LDS_AS void*)dst_, 16, 0, 0);        \
    }

#define ACC8(e, q, valid)                                                      \
    {                                                                          \
        float ve = ((valid) && ((e).x >> 6) == quarter)                        \
                       ? __int_as_float((e).y) : 0.f;                          \
        const __half2* hh = (const __half2*)&(q);                              \
        float2 f0 = __half22float2(hh[0]);                                     \
        float2 f1 = __half22float2(hh[1]);                                     \
        float2 f2 = __half22float2(hh[2]);                                     \
        float2 f3 = __half22float2(hh[3]);                                     \
        accA.x = fmaf(ve, f0.x, accA.x); accA.y = fmaf(ve, f0.y, accA.y);      \
        accA.z = fmaf(ve, f1.x, accA.z); accA.w = fmaf(ve, f1.y, accA.w);      \
        accB.x = fmaf(ve, f2.x, accB.x); accB.y = fmaf(ve, f2.y, accB.y);      \
        accB.z = fmaf(ve, f3.x, accB.z); accB.w = fmaf(ve, f3.y, accB.w);      \
    }

#define CONSUME(s)                                                             \
    {                                                                          \
        const char* wst = &wbuf[(s) % RING][0];                                \
        const int key = (s) * NW + wave;                                       \
        const int p0 = (int)lptr[key], p1 = (int)lptr[key + 1];                \
        for (int p = p0; p < p1; p += 4) {                                     \
            int2 e0 = cv[p];                                                   \
            int2 e1 = cv[min(p + 1, p1 - 1)];                                  \
            int2 e2 = cv[min(p + 2, p1 - 1)];                                  \
            int2 e3 = cv[min(p + 3, p1 - 1)];                                  \
            uint4 q0 = *(const uint4*)(wst + ((e0.x & 63) << 8) + loff);       \
            uint4 q1 = *(const uint4*)(wst + ((e1.x & 63) << 8) + loff);       \
            uint4 q2 = *(const uint4*)(wst + ((e2.x & 63) << 8) + loff);       \
            uint4 q3 = *(const uint4*)(wst + ((e3.x & 63) << 8) + loff);       \
            ACC8(e0, q0, true);                                                \
            ACC8(e1, q1, p + 1 < p1);                                          \
            ACC8(e2, q2, p + 2 < p1);                                          \
            ACC8(e3, q3, p + 3 < p1);                                          \
        }                                                                      \
    }

    // prologue: issue stages 0..3; land {0,1}; publish
    ISSUE(0); ISSUE(1); ISSUE(2); ISSUE(3);
    asm volatile("s_waitcnt vmcnt(2)" ::: "memory");
    __builtin_amdgcn_sched_barrier(0);
    __builtin_amdgcn_s_barrier();
    __builtin_amdgcn_sched_barrier(0);

    for (int g = 0; g < NSTAGES / 2; ++g) {
        const int t0 = 2 * g + 4;
        if (t0 + 1 < NSTAGES) { ISSUE(t0); ISSUE(t0 + 1); }
        CONSUME(2 * g);
        CONSUME(2 * g + 1);
        if (t0 + 1 < NSTAGES) {
            asm volatile("s_waitcnt vmcnt(2)" ::: "memory");  // land next group
        } else {
            asm volatile("s_waitcnt vmcnt(0)" ::: "memory");  // tail drain
        }
        __builtin_amdgcn_sched_barrier(0);
        __builtin_amdgcn_s_barrier();
        __builtin_amdgcn_sched_barrier(0);
    }
#undef ISSUE
#undef ACC8
#undef CONSUME

    // ---- epilogue: quarter q owns row r0 + wave*4 + q ----
    float* orow = out + (size_t)(r0 + wave * 4 + quarter) * OUT_UNITS + (sub << 3);
    *(float4*)orow = accA;
    *((float4*)(orow + 4)) = accB;
}

extern "C" void kernel_launch(void* const* d_in, const int* in_sizes, int n_in,
                              void* d_out, int out_size, void* d_ws, size_t ws_size,
                              hipStream_t stream) {
    const float* vals = (const float*)d_in[0];
    const float* w    = (const float*)d_in[1];
    const int*   rows = (const int*)d_in[2];
    const int*   cols = (const int*)d_in[3];
    float* out = (float*)d_out;

    const int nnz    = in_sizes[0];
    const int n_rows = out_size / OUT_UNITS;  // 16384
    const int w_n    = in_sizes[1];           // 8192*128
    const int n4     = w_n / 4;

    // ws layout: [0, 64KB+4) row_start ; [128KB, 128KB+2MB) w fp16
    int*    row_start = (int*)d_ws;
    __half* wh        = (__half*)((char*)d_ws + (128 << 10));

    const int prep_threads = (nnz > n4) ? nnz : n4;
    prep<<<(prep_threads + 255) / 256, 256, 0, stream>>>(
        (const float4*)w, (uint2*)wh, n4, rows, row_start, nnz, n_rows);
    spmm_sweep3<<<n_rows / RPB, NTHREADS, 0, stream>>>(
        vals, wh, cols, row_start, out);
}

// Round 7
// 132.765 us; speedup vs baseline: 1.3483x; 1.3483x over previous
//
#include <hip/hip_runtime.h>
#include <hip/hip_fp16.h>

#define OUT_UNITS 128
#define RPB 64                 // rows per block (grid 256 = 1 block/CU)
#define NTHREADS 1024          // 16 waves
#define NW 16
#define SROWS 128              // w-rows per sweep stage
#define SBYTES (SROWS * OUT_UNITS * 2)   // 32 KB fp16
#define NSTAGES 64             // 8192 / 128
#define RING 3                 // 96 KB ring
#define NKEY (NSTAGES * RPB)   // 4096 buckets: (stage, rowInBlock)
#define CV_CAP 4608            // block nnz: mean 4096, sigma 64 -> +8 sigma

#define GLOBAL_AS __attribute__((address_space(1)))
#define LDS_AS    __attribute__((address_space(3)))

// ---------------- Kernel 0: fused prep (round-0 proven) ---------------------
__global__ void prep(const float4* __restrict__ w4, uint2* __restrict__ wh, int n4,
                     const int* __restrict__ rows, int* __restrict__ row_start,
                     int nnz, int n_rows) {
    int i = blockIdx.x * blockDim.x + threadIdx.x;
    if (i < n4) {
        float4 f = w4[i];
        __half2 h01 = __floats2half2_rn(f.x, f.y);
        __half2 h23 = __floats2half2_rn(f.z, f.w);
        wh[i] = make_uint2(*(unsigned*)&h01, *(unsigned*)&h23);
    }
    if (i < nnz) {
        int cur = rows[i];
        if (i == 0) {
            for (int r = 0; r <= cur; ++r) row_start[r] = 0;
        } else {
            int prev = rows[i - 1];
            for (int r = prev + 1; r <= cur; ++r) row_start[r] = i;
        }
        if (i == nnz - 1) {
            for (int r = cur + 1; r <= n_rows; ++r) row_start[r] = nnz;
        }
    }
}

// ---------------- Kernel 1: bucketed sweep + counted-vmcnt ------------------
// Round 7 = round-5 consume x round-6 schedule.
// r5 proved: (stage,row) buckets, quarter-owned, are cheap (no redundancy;
//   divergent quarter loop costs ~E[max 4 Poisson(1)]=2.3 iter/stage) but its
//   per-stage __syncthreads() drained vmcnt -> serial L2 latency (2400 cyc/st).
// r6 proved: raw s_barrier + counted vmcnt(2) keeps the gload_lds ring in
//   flight across barriers; but its wave-uniform predicated consume was 8x
//   issue bloat (VALUBusy 53%, 120us).
// Here: per stage s: ISSUE(s+2) [2 x 1KB gload_lds/wave]; CONSUME(s) (landed
// pre-barrier, zero wait); vmcnt(2) lands stage s+1, leaves s+2 in flight;
// raw barrier. Ring-3: ISSUE(s+2) overwrites stage s-1's slot, consumed by
// all waves before the end-of-(s-1) barrier. Stream floor 585 cyc/stage;
// consume issue ~300 cyc/SIMD hides under it.
// cv packed int2{c&127, v} (single LDS read); bucket array collapsed to one
// u32[4096]: after scatter, bkt[k] = bucket END, so start[k] = bkt[k-1].
__global__ __launch_bounds__(NTHREADS, 4)
void spmm_sweep4(const float* __restrict__ vals,
                 const __half* __restrict__ wh,
                 const int* __restrict__ cols,
                 const int* __restrict__ row_start,
                 float* __restrict__ out) {
    __shared__ __align__(16) char wbuf[RING][SBYTES];  // 96 KB
    __shared__ int2     cv[CV_CAP];                    // 36 KB {c&127, v}
    __shared__ unsigned bkt[NKEY];                     // 16 KB starts->ends
    __shared__ unsigned wtot[NW], woff[NW];

    const int tid     = threadIdx.x;
    const int wave    = __builtin_amdgcn_readfirstlane(tid >> 6);
    const int lane    = tid & 63;
    const int quarter = lane >> 4;
    const int sub     = lane & 15;
    const int loff    = sub << 4;
    const int r0      = blockIdx.x * RPB;

    // ---- sort phase: counting-sort nnz by (stage, rowInBlock) ----
    for (int k = tid; k < NKEY; k += NTHREADS) bkt[k] = 0;
    __syncthreads();

    int rs[5];
#pragma unroll
    for (int j = 0; j <= 4; ++j) rs[j] = row_start[r0 + wave * 4 + j];

#pragma unroll
    for (int j = 0; j < 4; ++j)
        for (int i = rs[j] + lane; i < rs[j + 1]; i += 64) {
            int c = cols[i];
            atomicAdd(&bkt[((unsigned)c >> 7) * RPB + wave * 4 + j], 1u);
        }
    __syncthreads();

    // exclusive prefix over 4096 buckets (4 per thread, in place)
    const int kb = tid << 2;
    unsigned h[4], lsum = 0;
#pragma unroll
    for (int t = 0; t < 4; ++t) { h[t] = bkt[kb + t]; lsum += h[t]; }
    unsigned sc = lsum;
#pragma unroll
    for (int d = 1; d < 64; d <<= 1) {
        unsigned u = __shfl_up(sc, d);
        if (lane >= d) sc += u;
    }
    if (lane == 63) wtot[wave] = sc;
    const unsigned lex = sc - lsum;
    __syncthreads();
    if (wave == 0 && lane < NW) {
        unsigned t = wtot[lane], s2 = t;
#pragma unroll
        for (int d = 1; d < NW; d <<= 1) {
            unsigned u = __shfl_up(s2, d);
            if (lane >= d) s2 += u;
        }
        woff[lane] = s2 - t;
    }
    __syncthreads();
    unsigned base = woff[wave] + lex;
#pragma unroll
    for (int t = 0; t < 4; ++t) { bkt[kb + t] = base; base += h[t]; }
    __syncthreads();

    // scatter: cursors advance starts -> ends
#pragma unroll
    for (int j = 0; j < 4; ++j)
        for (int i = rs[j] + lane; i < rs[j + 1]; i += 64) {
            int c = cols[i];
            float v = vals[i];
            unsigned pos = atomicAdd(&bkt[((unsigned)c >> 7) * RPB + wave * 4 + j], 1u);
            cv[pos] = make_int2(c & 127, __float_as_int(v));
        }
    __syncthreads();   // full drain; vmcnt clean before stream discipline

    // ---- sweep phase ----
    const char* __restrict__ whb = (const char*)wh;
    float4 accA = make_float4(0.f, 0.f, 0.f, 0.f);
    float4 accB = make_float4(0.f, 0.f, 0.f, 0.f);

#define ISSUE(t)                                                               \
    {                                                                          \
        const char* src_ = whb + (size_t)(t) * SBYTES + (wave << 11) + (lane << 4); \
        char* dst_ = &wbuf[(t) % RING][wave << 11];                            \
        __builtin_amdgcn_global_load_lds((const GLOBAL_AS void*)src_,          \
                                         (LDS_AS void*)dst_, 16, 0, 0);        \
        __builtin_amdgcn_global_load_lds((const GLOBAL_AS void*)(src_ + 1024), \
                                         (LDS_AS void*)(dst_ + 1024), 16, 0, 0);\
    }

    // prologue: issue stages 0,1 (4 loads); land stage 0; publish
    ISSUE(0); ISSUE(1);
    asm volatile("s_waitcnt vmcnt(2)" ::: "memory");
    __builtin_amdgcn_sched_barrier(0);
    __builtin_amdgcn_s_barrier();
    __builtin_amdgcn_sched_barrier(0);

    for (int s = 0; s < NSTAGES; ++s) {
        if (s + 2 < NSTAGES) ISSUE(s + 2);

        // consume stage s (landed before previous barrier; zero wait)
        const char* wst = &wbuf[s % RING][0];
        const int key = (s << 6) + (wave << 2) + quarter;
        const int p1 = (int)bkt[key];
        const int p0 = key ? (int)bkt[key - 1] : 0;
        for (int p = p0; p < p1; ++p) {
            int2 e = cv[p];
            float v = __int_as_float(e.y);
            uint4 q4 = *(const uint4*)(wst + (e.x << 8) + loff);
            const __half2* hh = (const __half2*)&q4;
            float2 f0 = __half22float2(hh[0]);
            float2 f1 = __half22float2(hh[1]);
            float2 f2 = __half22float2(hh[2]);
            float2 f3 = __half22float2(hh[3]);
            accA.x = fmaf(v, f0.x, accA.x); accA.y = fmaf(v, f0.y, accA.y);
            accA.z = fmaf(v, f1.x, accA.z); accA.w = fmaf(v, f1.y, accA.w);
            accB.x = fmaf(v, f2.x, accB.x); accB.y = fmaf(v, f2.y, accB.y);
            accB.z = fmaf(v, f3.x, accB.z); accB.w = fmaf(v, f3.y, accB.w);
        }

        if (s + 2 < NSTAGES) {
            asm volatile("s_waitcnt vmcnt(2)" ::: "memory");  // land stage s+1
        } else {
            asm volatile("s_waitcnt vmcnt(0)" ::: "memory");  // tail drain
        }
        __builtin_amdgcn_sched_barrier(0);
        __builtin_amdgcn_s_barrier();
        __builtin_amdgcn_sched_barrier(0);
    }
#undef ISSUE

    // ---- epilogue: quarter q owns row r0 + wave*4 + q ----
    float* orow = out + (size_t)(r0 + (wave << 2) + quarter) * OUT_UNITS + (sub << 3);
    *(float4*)orow = accA;
    *((float4*)(orow + 4)) = accB;
}

extern "C" void kernel_launch(void* const* d_in, const int* in_sizes, int n_in,
                              void* d_out, int out_size, void* d_ws, size_t ws_size,
                              hipStream_t stream) {
    const float* vals = (const float*)d_in[0];
    const float* w    = (const float*)d_in[1];
    const int*   rows = (const int*)d_in[2];
    const int*   cols = (const int*)d_in[3];
    float* out = (float*)d_out;

    const int nnz    = in_sizes[0];
    const int n_rows = out_size / OUT_UNITS;  // 16384
    const int w_n    = in_sizes[1];           // 8192*128
    const int n4     = w_n / 4;

    // ws layout: [0, 64KB+4) row_start ; [128KB, 128KB+2MB) w fp16
    int*    row_start = (int*)d_ws;
    __half* wh        = (__half*)((char*)d_ws + (128 << 10));

    const int prep_threads = (nnz > n4) ? nnz : n4;
    prep<<<(prep_threads + 255) / 256, 256, 0, stream>>>(
        (const float4*)w, (uint2*)wh, n4, rows, row_start, nnz, n_rows);
    spmm_sweep4<<<n_rows / RPB, NTHREADS, 0, stream>>>(
        vals, wh, cols, row_start, out);
}